// Round 1
// baseline (1297.688 us; speedup 1.0000x reference)
//
#include <hip/hip_runtime.h>

// PiCANet-L attention block, fp32 baseline.
// x[4,256,64,64] -> conv1(7x7 dil2 pad6, 256->128)+b1 -> conv2(1x1,128->49)+b2
// -> softmax(ch) -> 49-tap dilated gather of x.
//
// ws layout: k1 [4*128*64*64] floats (8 MB), attn [4*49*64*64] floats (3.2 MB)

#define HW 64
#define CIN 256
#define OC1 128
#define NJ 49

// ---------------------------------------------------------------------------
// conv1: grid (2, 64, 4) = (w-half, h, b); block 256.
// Block computes 32 pixels x 128 oc. Thread: 4 px x 4 oc register tile.
// ---------------------------------------------------------------------------
__global__ __launch_bounds__(256, 2) void conv1_kernel(
    const float* __restrict__ x, const float* __restrict__ w1,
    const float* __restrict__ b1, float* __restrict__ k1)
{
    __shared__ float xs[7][44];        // input rows for current ic
    __shared__ float ws2[NJ * 132];    // ws2[k*132 + oc], k = u*7+v (pad 132: write conflicts)

    const int wh = blockIdx.x, h = blockIdx.y, b = blockIdx.z;
    const int t = threadIdx.x;
    const int p = t & 7;    // pixel group: w = w0 + 4p + i
    const int o = t >> 3;   // oc group:    oc = 4o + j
    const int w0 = wh * 32;

    float acc[4][4];
    #pragma unroll
    for (int i = 0; i < 4; ++i)
        #pragma unroll
        for (int j = 0; j < 4; ++j) acc[i][j] = 0.f;

    const float* xb = x + (size_t)(b * CIN) * (HW * HW);

    for (int ic = 0; ic < CIN; ++ic) {
        __syncthreads();
        // stage input: 7 rows (h-6+2u) x 44 cols (w0-6 .. w0+37), zero-padded
        for (int f = t; f < 7 * 44; f += 256) {
            int r = f / 44, ci = f - r * 44;
            int row = h - 6 + 2 * r;
            int col = w0 - 6 + ci;
            float v = 0.f;
            if ((unsigned)row < 64u && (unsigned)col < 64u)
                v = xb[ic * 4096 + row * 64 + col];
            xs[r][ci] = v;
        }
        // stage weights for this ic: ws2[k*132+oc] = w1[oc,ic,k]
        for (int f = t; f < NJ * OC1; f += 256) {
            int oc = f / NJ, k = f - oc * NJ;
            ws2[k * 132 + oc] = w1[oc * (CIN * NJ) + ic * NJ + k];
        }
        __syncthreads();

        #pragma unroll
        for (int u = 0; u < 7; ++u) {
            float xv[16];
            #pragma unroll
            for (int q = 0; q < 4; ++q) {
                const float4 t4 = *(const float4*)&xs[u][4 * p + 4 * q];
                xv[4 * q + 0] = t4.x; xv[4 * q + 1] = t4.y;
                xv[4 * q + 2] = t4.z; xv[4 * q + 3] = t4.w;
            }
            #pragma unroll
            for (int v = 0; v < 7; ++v) {
                const float4 wv = *(const float4*)&ws2[(u * 7 + v) * 132 + 4 * o];
                #pragma unroll
                for (int i = 0; i < 4; ++i) {
                    const float xval = xv[2 * v + i];
                    acc[i][0] += xval * wv.x;
                    acc[i][1] += xval * wv.y;
                    acc[i][2] += xval * wv.z;
                    acc[i][3] += xval * wv.w;
                }
            }
        }
    }

    float* kb = k1 + ((size_t)(b * OC1) * HW + h) * HW;
    #pragma unroll
    for (int j = 0; j < 4; ++j) {
        const int oc = 4 * o + j;
        const float bias = b1[oc];
        float4 st;
        st.x = acc[0][j] + bias;
        st.y = acc[1][j] + bias;
        st.z = acc[2][j] + bias;
        st.w = acc[3][j] + bias;
        *(float4*)&kb[oc * 4096 + w0 + 4 * p] = st;
    }
}

// ---------------------------------------------------------------------------
// conv2 (1x1, 128->49) + bias + softmax over 49 -> attn
// grid (64, 4) = (h, b); block 256. Thread: pixel w = t&63, j-stride group t>>6.
// ---------------------------------------------------------------------------
__global__ __launch_bounds__(256, 2) void conv2_softmax_kernel(
    const float* __restrict__ k1, const float* __restrict__ w2,
    const float* __restrict__ b2, float* __restrict__ attn)
{
    __shared__ float k1s[OC1 * 64];  // 32 KB
    __shared__ float k2s[NJ * 64];   // 12.25 KB
    const int h = blockIdx.x, b = blockIdx.y;
    const int t = threadIdx.x;

    const float* kb = k1 + ((size_t)(b * OC1) * HW + h) * HW;
    for (int f = t; f < OC1 * 64; f += 256) {
        int oc = f >> 6, w = f & 63;
        k1s[f] = kb[oc * 4096 + w];
    }
    __syncthreads();

    const int w = t & 63, jg = t >> 6;   // jg wave-uniform
    for (int j = jg; j < NJ; j += 4) {
        float s = b2[j];
        const float* wrow = w2 + j * OC1;
        #pragma unroll 8
        for (int oc = 0; oc < OC1; ++oc)
            s += k1s[oc * 64 + w] * wrow[oc];
        k2s[j * 64 + w] = s;
    }
    __syncthreads();

    float m = -1e30f;
    for (int j = 0; j < NJ; ++j) m = fmaxf(m, k2s[j * 64 + w]);
    float s = 0.f;
    for (int j = 0; j < NJ; ++j) s += __expf(k2s[j * 64 + w] - m);
    const float inv = 1.f / s;

    float* ab = attn + ((size_t)(b * NJ) * HW + h) * HW;
    for (int j = jg; j < NJ; j += 4)
        ab[j * 4096 + w] = __expf(k2s[j * 64 + w] - m) * inv;
}

// ---------------------------------------------------------------------------
// gather: out[b,c,h,w] = sum_{u,v} attn[b,u*7+v,h,w] * x[b,c,h+2u-6,w+2v-6]
// grid (8, 64, 4) = (c-chunk/32, h, b); block 256. Thread: (w, 8 channels).
// ---------------------------------------------------------------------------
__global__ __launch_bounds__(256, 2) void gather_kernel(
    const float* __restrict__ x, const float* __restrict__ attn,
    float* __restrict__ out)
{
    __shared__ float as[NJ * 64];
    const int cg = blockIdx.x, h = blockIdx.y, b = blockIdx.z;
    const int t = threadIdx.x;

    const float* ab = attn + ((size_t)(b * NJ) * HW + h) * HW;
    for (int f = t; f < NJ * 64; f += 256)
        as[f] = ab[(f >> 6) * 4096 + (f & 63)];
    __syncthreads();

    const int w = t & 63, cs = t >> 6;
    const int c0 = cg * 32 + cs * 8;
    const float* xb = x + (size_t)(b * CIN + c0) * 4096;

    float acc[8];
    #pragma unroll
    for (int i = 0; i < 8; ++i) acc[i] = 0.f;

    #pragma unroll
    for (int u = 0; u < 7; ++u) {
        const int row = h + 2 * u - 6;
        if ((unsigned)row >= 64u) continue;   // block-uniform
        #pragma unroll
        for (int v = 0; v < 7; ++v) {
            const int col = w + 2 * v - 6;
            const float a = as[(u * 7 + v) * 64 + w];
            if ((unsigned)col < 64u) {
                #pragma unroll
                for (int i = 0; i < 8; ++i)
                    acc[i] += a * xb[i * 4096 + row * 64 + col];
            }
        }
    }

    float* ob = out + (size_t)(b * CIN + c0) * 4096 + h * 64;
    #pragma unroll
    for (int i = 0; i < 8; ++i) ob[i * 4096 + w] = acc[i];
}

// ---------------------------------------------------------------------------
extern "C" void kernel_launch(void* const* d_in, const int* in_sizes, int n_in,
                              void* d_out, int out_size, void* d_ws, size_t ws_size,
                              hipStream_t stream) {
    const float* x  = (const float*)d_in[0];
    const float* w1 = (const float*)d_in[1];
    const float* b1 = (const float*)d_in[2];
    const float* w2 = (const float*)d_in[3];
    const float* b2 = (const float*)d_in[4];
    float* out = (float*)d_out;

    float* k1   = (float*)d_ws;                 // 4*128*64*64 = 2,097,152 floats
    float* attn = k1 + 4 * OC1 * HW * HW;       // 4*49*64*64  =   802,816 floats

    conv1_kernel<<<dim3(2, HW, 4), 256, 0, stream>>>(x, w1, b1, k1);
    conv2_softmax_kernel<<<dim3(HW, 4), 256, 0, stream>>>(k1, w2, b2, attn);
    gather_kernel<<<dim3(8, HW, 4), 256, 0, stream>>>(x, attn, out);
}

// Round 2
// 265.864 us; speedup vs baseline: 4.8810x; 4.8810x over previous
//
#include <hip/hip_runtime.h>

#define HW 64
#define CIN 256
#define OC1 128
#define NJ 49
#define XSTR 136   // LDS ic-stride (shorts): 272B = 16B-aligned, odd*16 -> 2-way aliasing only

typedef short bf16x8 __attribute__((ext_vector_type(8)));
typedef float f32x4 __attribute__((ext_vector_type(4)));

// round-to-nearest-even f32->bf16, packed pair (a=low, b=high)
__device__ __forceinline__ unsigned f2bf_pack(float a, float b) {
    unsigned ua = __float_as_uint(a);
    ua += 0x7FFF + ((ua >> 16) & 1);
    unsigned ub = __float_as_uint(b);
    ub += 0x7FFF + ((ub >> 16) & 1);
    return (ua >> 16) | (ub & 0xFFFF0000u);
}

// ---------------------------------------------------------------------------
// w1 fp32 [128 oc][256 ic][49 tap] -> w1t bf16 [49][128 oc][256 ic]
// thread = (oc, ic): reads 49 contiguous floats, writes lane-contiguous per tap.
// ---------------------------------------------------------------------------
__global__ void wtrans_kernel(const float* __restrict__ w1,
                              unsigned short* __restrict__ w1t) {
    int tid = blockIdx.x * 256 + threadIdx.x;   // 32768 = 128*256
    int oc = tid >> 8, ic = tid & 255;
    const float* src = w1 + ((size_t)oc * 256 + ic) * 49;
    #pragma unroll
    for (int tap = 0; tap < 49; ++tap) {
        unsigned u = __float_as_uint(src[tap]);
        u += 0x7FFF + ((u >> 16) & 1);
        w1t[((size_t)tap * 128 + oc) * 256 + ic] = (unsigned short)(u >> 16);
    }
}

// ---------------------------------------------------------------------------
// conv1 implicit GEMM, bf16 MFMA 16x16x32.
// grid (2 kz, 32 hp, 4 b); block 256 = 4 waves. Block: 128 oc x 128 px (rows h0,h0+1),
// K-half = 128 ic x 49 taps. Wave: 64 oc x 64 px = 4x4 frags.
// A (M=oc) = w1t from global (L2-resident); B (N=px) = xs from LDS (ic-contig).
// P[kz][b][oc][h][w] fp32 partials.
// ---------------------------------------------------------------------------
__global__ __launch_bounds__(256) void conv1_mfma_kernel(
    const float* __restrict__ x, const unsigned short* __restrict__ w1t,
    float* __restrict__ P)
{
    __shared__ unsigned xs32[2 * 80 * XSTR / 2];   // 43,520 B: [row][col 80][ic 128(+pad)]

    const int kz = blockIdx.x, hp = blockIdx.y, b = blockIdx.z;
    const int h0 = hp * 2;
    const int t = threadIdx.x;
    const int lane = t & 63, wv = t >> 6;
    const int oc_off = (wv & 1) * 64;
    const int px_off = (wv >> 1) * 64;
    const int ri = px_off >> 6;            // wave-uniform pixel row (0/1)
    const int l15 = lane & 15;
    const int quad = lane >> 4;
    const int klo = quad * 8;

    f32x4 acc[4][4];                        // [of][pf]
    #pragma unroll
    for (int i = 0; i < 4; ++i)
        #pragma unroll
        for (int j = 0; j < 4; ++j) acc[i][j] = (f32x4){0.f, 0.f, 0.f, 0.f};

    const float* xb = x + ((size_t)b * CIN + kz * 128) * 4096;
    const unsigned short* wbase = w1t + (size_t)(oc_off + l15) * 256 + kz * 128 + klo;

    for (int u = 0; u < 7; ++u) {
        __syncthreads();
        // stage xs: 2 rows x 128 ic x 80 cols (stored col = src col + 8; zero pad)
        #pragma unroll
        for (int i = 0; i < 10; ++i) {
            int f = t + i * 256;                 // 0..2559
            int row_i = (f >= 1280) ? 1 : 0;
            int rem = f - row_i * 1280;
            int icp = rem / 20;                  // ic pair 0..63
            int c4 = rem - icp * 20;             // float4 col group 0..19
            int r = h0 + row_i + 2 * u - 6;
            float4 g0 = make_float4(0.f, 0.f, 0.f, 0.f);
            float4 g1 = g0;
            if ((unsigned)r < 64u && (unsigned)(c4 - 2) <= 15u) {
                const float* p = xb + (size_t)(2 * icp) * 4096 + r * 64 + 4 * c4 - 8;
                g0 = *(const float4*)p;
                g1 = *(const float4*)(p + 4096);
            }
            unsigned* dst = &xs32[(row_i * 80 + 4 * c4) * (XSTR / 2) + icp];
            dst[0]             = f2bf_pack(g0.x, g1.x);
            dst[XSTR / 2]      = f2bf_pack(g0.y, g1.y);
            dst[2 * (XSTR / 2)] = f2bf_pack(g0.z, g1.z);
            dst[3 * (XSTR / 2)] = f2bf_pack(g0.w, g1.w);
        }
        __syncthreads();

        #pragma unroll
        for (int v = 0; v < 7; ++v) {
            const int tap = u * 7 + v;
            const unsigned short* wp = wbase + (size_t)tap * (128 * 256);
            const unsigned short* xp = (const unsigned short*)xs32
                                       + (ri * 80 + 2 * v + 2) * XSTR + klo;
            #pragma unroll
            for (int ks = 0; ks < 4; ++ks) {
                bf16x8 wf[4], xf[4];
                #pragma unroll
                for (int of = 0; of < 4; ++of)
                    wf[of] = *(const bf16x8*)(wp + of * (16 * 256) + ks * 32);
                #pragma unroll
                for (int pf = 0; pf < 4; ++pf)
                    xf[pf] = *(const bf16x8*)(xp + (pf * 16 + l15) * XSTR + ks * 32);
                #pragma unroll
                for (int of = 0; of < 4; ++of)
                    #pragma unroll
                    for (int pf = 0; pf < 4; ++pf)
                        acc[of][pf] = __builtin_amdgcn_mfma_f32_16x16x32_bf16(
                            wf[of], xf[pf], acc[of][pf], 0, 0, 0);
            }
        }
    }

    // epilogue: D row = oc (quad*4+reg), col = px (l15) -> coalesced over w
    float* Pb = P + ((size_t)kz * 4 + b) * (128 * 4096) + (h0 + ri) * 64;
    #pragma unroll
    for (int of = 0; of < 4; ++of) {
        const int oc = oc_off + of * 16 + quad * 4;
        #pragma unroll
        for (int pf = 0; pf < 4; ++pf) {
            const int w = pf * 16 + l15;
            #pragma unroll
            for (int reg = 0; reg < 4; ++reg)
                Pb[(size_t)(oc + reg) * 4096 + w] = acc[of][pf][reg];
        }
    }
}

// ---------------------------------------------------------------------------
// conv2 (1x1, 128->49) + b2 + softmax; fuses P0+P1+b1 reduction.
// grid (64 h, 4 b); block 256.
// ---------------------------------------------------------------------------
__global__ __launch_bounds__(256) void conv2_softmax_kernel(
    const float* __restrict__ P, const float* __restrict__ w2,
    const float* __restrict__ b2, const float* __restrict__ b1,
    float* __restrict__ attn)
{
    __shared__ float k1s[OC1 * 64];  // 32 KB
    __shared__ float k2s[NJ * 64];
    const int h = blockIdx.x, b = blockIdx.y;
    const int t = threadIdx.x;

    const float* p0 = P + (size_t)b * (128 * 4096) + h * 64;
    const float* p1 = P + (size_t)(4 + b) * (128 * 4096) + h * 64;
    for (int f = t; f < OC1 * 64; f += 256) {
        int oc = f >> 6, w = f & 63;
        k1s[f] = p0[(size_t)oc * 4096 + w] + p1[(size_t)oc * 4096 + w] + b1[oc];
    }
    __syncthreads();

    const int w = t & 63, jg = t >> 6;
    for (int j = jg; j < NJ; j += 4) {
        float s = b2[j];
        const float* wrow = w2 + j * OC1;
        #pragma unroll 8
        for (int oc = 0; oc < OC1; ++oc)
            s += k1s[oc * 64 + w] * wrow[oc];
        k2s[j * 64 + w] = s;
    }
    __syncthreads();

    float m = -1e30f;
    for (int j = 0; j < NJ; ++j) m = fmaxf(m, k2s[j * 64 + w]);
    float s = 0.f;
    for (int j = 0; j < NJ; ++j) s += __expf(k2s[j * 64 + w] - m);
    const float inv = 1.f / s;

    float* ab = attn + ((size_t)(b * NJ) * HW + h) * HW;
    for (int j = jg; j < NJ; j += 4)
        ab[j * 4096 + w] = __expf(k2s[j * 64 + w] - m) * inv;
}

// ---------------------------------------------------------------------------
// gather: out[b,c,h,w] = sum_{u,v} attn[b,u*7+v,h,w] * x[b,c,h+2u-6,w+2v-6]
// ---------------------------------------------------------------------------
__global__ __launch_bounds__(256) void gather_kernel(
    const float* __restrict__ x, const float* __restrict__ attn,
    float* __restrict__ out)
{
    __shared__ float as[NJ * 64];
    const int cg = blockIdx.x, h = blockIdx.y, b = blockIdx.z;
    const int t = threadIdx.x;

    const float* ab = attn + ((size_t)(b * NJ) * HW + h) * HW;
    for (int f = t; f < NJ * 64; f += 256)
        as[f] = ab[(f >> 6) * 4096 + (f & 63)];
    __syncthreads();

    const int w = t & 63, cs = t >> 6;
    const int c0 = cg * 32 + cs * 8;
    const float* xb = x + (size_t)(b * CIN + c0) * 4096;

    float acc[8];
    #pragma unroll
    for (int i = 0; i < 8; ++i) acc[i] = 0.f;

    #pragma unroll
    for (int u = 0; u < 7; ++u) {
        const int row = h + 2 * u - 6;
        if ((unsigned)row >= 64u) continue;
        #pragma unroll
        for (int v = 0; v < 7; ++v) {
            const int col = w + 2 * v - 6;
            const float a = as[(u * 7 + v) * 64 + w];
            if ((unsigned)col < 64u) {
                #pragma unroll
                for (int i = 0; i < 8; ++i)
                    acc[i] += a * xb[i * 4096 + row * 64 + col];
            }
        }
    }

    float* ob = out + (size_t)(b * CIN + c0) * 4096 + h * 64;
    #pragma unroll
    for (int i = 0; i < 8; ++i) ob[i * 4096 + w] = acc[i];
}

// ---------------------------------------------------------------------------
// ws: w1t bf16 [49*128*256] = 3.2MB | P fp32 [2][4][128][64][64] = 16.8MB |
//     attn fp32 [4][49][64][64] = 3.2MB   (total ~23.2 MB)
// ---------------------------------------------------------------------------
extern "C" void kernel_launch(void* const* d_in, const int* in_sizes, int n_in,
                              void* d_out, int out_size, void* d_ws, size_t ws_size,
                              hipStream_t stream) {
    const float* x  = (const float*)d_in[0];
    const float* w1 = (const float*)d_in[1];
    const float* b1 = (const float*)d_in[2];
    const float* w2 = (const float*)d_in[3];
    const float* b2 = (const float*)d_in[4];
    float* out = (float*)d_out;

    unsigned short* w1t = (unsigned short*)d_ws;
    float* P    = (float*)d_ws + 802816;       // after 3,211,264 B of w1t
    float* attn = P + 2 * 4 * 128 * 4096;      // after 16.8 MB of partials

    wtrans_kernel<<<128, 256, 0, stream>>>(w1, w1t);
    conv1_mfma_kernel<<<dim3(2, 32, 4), 256, 0, stream>>>(x, w1t, P);
    conv2_softmax_kernel<<<dim3(HW, 4), 256, 0, stream>>>(P, w2, b2, b1, attn);
    gather_kernel<<<dim3(8, HW, 4), 256, 0, stream>>>(x, attn, out);
}

// Round 3
// 234.664 us; speedup vs baseline: 5.5300x; 1.1330x over previous
//
#include <hip/hip_runtime.h>

#define HW 64
#define CIN 256
#define OC1 128
#define NJ 49
#define KZ 4        // K-split factor: each conv1 block does 64 ic x 49 taps
#define XSTR 72     // LDS ic-stride (shorts): 144B, 16B-aligned; read lane-step 36 words = bank+4 (free)

typedef short bf16x8 __attribute__((ext_vector_type(8)));
typedef float f32x4 __attribute__((ext_vector_type(4)));

__device__ __forceinline__ unsigned f2bf_pack(float a, float b) {
    unsigned ua = __float_as_uint(a);
    ua += 0x7FFF + ((ua >> 16) & 1);
    unsigned ub = __float_as_uint(b);
    ub += 0x7FFF + ((ub >> 16) & 1);
    return (ua >> 16) | (ub & 0xFFFF0000u);
}

// ---------------------------------------------------------------------------
// w1 fp32 [128 oc][256 ic][49 tap] -> w1t bf16 [49][128 oc][256 ic]
// 512 blocks x 64 thr: block=(oc, ic-quarter); lane reads 49 contiguous floats.
// ---------------------------------------------------------------------------
__global__ __launch_bounds__(64) void wtrans_kernel(const float* __restrict__ w1,
                                                    unsigned short* __restrict__ w1t) {
    int oc = blockIdx.x >> 2, icq = blockIdx.x & 3;
    int ic = icq * 64 + threadIdx.x;
    const float* src = w1 + ((size_t)oc * 256 + ic) * 49;
    #pragma unroll
    for (int tap = 0; tap < 49; ++tap) {
        unsigned u = __float_as_uint(src[tap]);
        u += 0x7FFF + ((u >> 16) & 1);
        w1t[((size_t)tap * 128 + oc) * 256 + ic] = (unsigned short)(u >> 16);
    }
}

// ---------------------------------------------------------------------------
// conv1 implicit GEMM, bf16 MFMA 16x16x32, K-split 4.
// grid (4 kz, 32 hp, 4 b) = 512 blocks; block 256 = 4 waves; wave 64 oc x 64 px.
// Per-u staging is register-prefetched one u ahead to overlap global latency.
// ---------------------------------------------------------------------------
__global__ __launch_bounds__(256) void conv1_mfma_kernel(
    const float* __restrict__ x, const unsigned short* __restrict__ w1t,
    float* __restrict__ P)
{
    __shared__ unsigned xs32[2 * 80 * (XSTR / 2)];   // 23,040 B: [row][col 80][ic 64]

    const int kz = blockIdx.x, hp = blockIdx.y, b = blockIdx.z;
    const int h0 = hp * 2;
    const int t = threadIdx.x;
    const int lane = t & 63, wv = t >> 6;
    const int oc_off = (wv & 1) * 64;
    const int ri = wv >> 1;               // wave-uniform pixel row (0/1)
    const int l15 = lane & 15;
    const int quad = lane >> 4;
    const int klo = quad * 8;

    f32x4 acc[4][4];
    #pragma unroll
    for (int i = 0; i < 4; ++i)
        #pragma unroll
        for (int j = 0; j < 4; ++j) acc[i][j] = (f32x4){0.f, 0.f, 0.f, 0.f};

    const float* xb = x + ((size_t)b * CIN + kz * 64) * 4096;
    const unsigned short* wbase = w1t + (size_t)(oc_off + l15) * 256 + kz * 64 + klo;

    // staging decode (per prefetch slot i): f = t + i*256 in [0,1280)
    float4 pg0[5], pg1[5];
    int s_row[5], s_icp[5], s_c4[5];
    #pragma unroll
    for (int i = 0; i < 5; ++i) {
        int f = t + i * 256;
        int row_i = (f >= 640) ? 1 : 0;
        int rem = f - row_i * 640;
        int icp = rem / 20;
        s_row[i] = row_i; s_icp[i] = icp; s_c4[i] = rem - icp * 20;
    }

    #define ISSUE(UU)                                                          \
        _Pragma("unroll")                                                      \
        for (int i = 0; i < 5; ++i) {                                          \
            int r = h0 + s_row[i] + 2 * (UU) - 6;                              \
            float4 g0 = make_float4(0.f, 0.f, 0.f, 0.f), g1 = g0;              \
            if ((unsigned)r < 64u && (unsigned)(s_c4[i] - 2) <= 15u) {         \
                const float* p = xb + (size_t)(2 * s_icp[i]) * 4096            \
                                 + r * 64 + 4 * s_c4[i] - 8;                   \
                g0 = *(const float4*)p;                                        \
                g1 = *(const float4*)(p + 4096);                               \
            }                                                                  \
            pg0[i] = g0; pg1[i] = g1;                                          \
        }

    ISSUE(0);

    for (int u = 0; u < 7; ++u) {
        __syncthreads();
        #pragma unroll
        for (int i = 0; i < 5; ++i) {
            unsigned* dst = &xs32[(s_row[i] * 80 + 4 * s_c4[i]) * (XSTR / 2) + s_icp[i]];
            dst[0]              = f2bf_pack(pg0[i].x, pg1[i].x);
            dst[(XSTR / 2)]     = f2bf_pack(pg0[i].y, pg1[i].y);
            dst[2 * (XSTR / 2)] = f2bf_pack(pg0[i].z, pg1[i].z);
            dst[3 * (XSTR / 2)] = f2bf_pack(pg0[i].w, pg1[i].w);
        }
        __syncthreads();
        if (u < 6) { ISSUE(u + 1); }   // overlaps with tap loop below

        #pragma unroll
        for (int v = 0; v < 7; ++v) {
            const int tap = u * 7 + v;
            const unsigned short* wp = wbase + (size_t)tap * (128 * 256);
            const unsigned short* xp = (const unsigned short*)xs32
                                       + (ri * 80 + 2 * v + 2) * XSTR + klo;
            #pragma unroll
            for (int ks = 0; ks < 2; ++ks) {
                bf16x8 wf[4], xf[4];
                #pragma unroll
                for (int of = 0; of < 4; ++of)
                    wf[of] = *(const bf16x8*)(wp + of * 4096 + ks * 32);
                #pragma unroll
                for (int pf = 0; pf < 4; ++pf)
                    xf[pf] = *(const bf16x8*)(xp + (pf * 16 + l15) * XSTR + ks * 32);
                #pragma unroll
                for (int of = 0; of < 4; ++of)
                    #pragma unroll
                    for (int pf = 0; pf < 4; ++pf)
                        acc[of][pf] = __builtin_amdgcn_mfma_f32_16x16x32_bf16(
                            wf[of], xf[pf], acc[of][pf], 0, 0, 0);
            }
        }
    }
    #undef ISSUE

    float* Pb = P + ((size_t)kz * 4 + b) * (128 * 4096) + (h0 + ri) * 64;
    #pragma unroll
    for (int of = 0; of < 4; ++of) {
        const int oc = oc_off + of * 16 + quad * 4;
        #pragma unroll
        for (int pf = 0; pf < 4; ++pf) {
            const int w = pf * 16 + l15;
            #pragma unroll
            for (int reg = 0; reg < 4; ++reg)
                Pb[(size_t)(oc + reg) * 4096 + w] = acc[of][pf][reg];
        }
    }
}

// ---------------------------------------------------------------------------
// conv2 (1x1, 128->49) + b2 + softmax; reduces 4 P partials + b1.
// grid (64 h, 4 b); block 1024 (16 waves) for latency hiding.
// ---------------------------------------------------------------------------
__global__ __launch_bounds__(1024) void conv2_softmax_kernel(
    const float* __restrict__ P, const float* __restrict__ w2,
    const float* __restrict__ b2, const float* __restrict__ b1,
    float* __restrict__ attn)
{
    __shared__ float k1s[OC1 * 64];  // 32 KB
    __shared__ float k2s[NJ * 64];
    const int h = blockIdx.x, b = blockIdx.y;
    const int t = threadIdx.x;

    const size_t hoff = (size_t)h * 64;
    const float* p0 = P + ((size_t)0 * 4 + b) * (128 * 4096) + hoff;
    const float* p1 = P + ((size_t)1 * 4 + b) * (128 * 4096) + hoff;
    const float* p2 = P + ((size_t)2 * 4 + b) * (128 * 4096) + hoff;
    const float* p3 = P + ((size_t)3 * 4 + b) * (128 * 4096) + hoff;
    for (int f = t; f < OC1 * 64; f += 1024) {
        int oc = f >> 6, w = f & 63;
        size_t idx = (size_t)oc * 4096 + w;
        k1s[f] = p0[idx] + p1[idx] + p2[idx] + p3[idx] + b1[oc];
    }
    __syncthreads();

    const int w = t & 63, jg = t >> 6;   // jg in 0..15, wave-uniform
    for (int j = jg; j < NJ; j += 16) {
        float s = b2[j];
        const float* wrow = w2 + j * OC1;
        #pragma unroll 8
        for (int oc = 0; oc < OC1; ++oc)
            s += k1s[oc * 64 + w] * wrow[oc];
        k2s[j * 64 + w] = s;
    }
    __syncthreads();

    float m = -1e30f;
    for (int j = 0; j < NJ; ++j) m = fmaxf(m, k2s[j * 64 + w]);
    float s = 0.f;
    for (int j = 0; j < NJ; ++j) s += __expf(k2s[j * 64 + w] - m);
    const float inv = 1.f / s;

    float* ab = attn + ((size_t)(b * NJ) * HW + h) * HW;
    for (int j = jg; j < NJ; j += 16)
        ab[j * 4096 + w] = __expf(k2s[j * 64 + w] - m) * inv;
}

// ---------------------------------------------------------------------------
// gather: out[b,c,h,w] = sum_{u,v} attn[b,u*7+v,h,w] * x[b,c,h+2u-6,w+2v-6]
// ---------------------------------------------------------------------------
__global__ __launch_bounds__(256) void gather_kernel(
    const float* __restrict__ x, const float* __restrict__ attn,
    float* __restrict__ out)
{
    __shared__ float as[NJ * 64];
    const int cg = blockIdx.x, h = blockIdx.y, b = blockIdx.z;
    const int t = threadIdx.x;

    const float* ab = attn + ((size_t)(b * NJ) * HW + h) * HW;
    for (int f = t; f < NJ * 64; f += 256)
        as[f] = ab[(f >> 6) * 4096 + (f & 63)];
    __syncthreads();

    const int w = t & 63, cs = t >> 6;
    const int c0 = cg * 32 + cs * 8;
    const float* xb = x + (size_t)(b * CIN + c0) * 4096;

    float acc[8];
    #pragma unroll
    for (int i = 0; i < 8; ++i) acc[i] = 0.f;

    #pragma unroll
    for (int u = 0; u < 7; ++u) {
        const int row = h + 2 * u - 6;
        if ((unsigned)row >= 64u) continue;
        #pragma unroll
        for (int v = 0; v < 7; ++v) {
            const int col = w + 2 * v - 6;
            const float a = as[(u * 7 + v) * 64 + w];
            if ((unsigned)col < 64u) {
                #pragma unroll
                for (int i = 0; i < 8; ++i)
                    acc[i] += a * xb[i * 4096 + row * 64 + col];
            }
        }
    }

    float* ob = out + (size_t)(b * CIN + c0) * 4096 + h * 64;
    #pragma unroll
    for (int i = 0; i < 8; ++i) ob[i * 4096 + w] = acc[i];
}

// ---------------------------------------------------------------------------
// ws: w1t bf16 3.2MB | P fp32 [4][4][128][64][64] = 33.6MB | attn 3.2MB  (~40MB)
// ---------------------------------------------------------------------------
extern "C" void kernel_launch(void* const* d_in, const int* in_sizes, int n_in,
                              void* d_out, int out_size, void* d_ws, size_t ws_size,
                              hipStream_t stream) {
    const float* x  = (const float*)d_in[0];
    const float* w1 = (const float*)d_in[1];
    const float* b1 = (const float*)d_in[2];
    const float* w2 = (const float*)d_in[3];
    const float* b2 = (const float*)d_in[4];
    float* out = (float*)d_out;

    unsigned short* w1t = (unsigned short*)d_ws;
    float* P    = (float*)d_ws + 802816;        // after 3,211,264 B of w1t
    float* attn = P + (size_t)KZ * 4 * 128 * 4096;

    wtrans_kernel<<<512, 64, 0, stream>>>(w1, w1t);
    conv1_mfma_kernel<<<dim3(KZ, 32, 4), 256, 0, stream>>>(x, w1t, P);
    conv2_softmax_kernel<<<dim3(HW, 4), 1024, 0, stream>>>(P, w2, b2, b1, attn);
    gather_kernel<<<dim3(8, HW, 4), 256, 0, stream>>>(x, attn, out);
}